// Round 6
// baseline (93.102 us; speedup 1.0000x reference)
//
#include <hip/hip_runtime.h>
#include <math.h>

#define TPB 512   // 8-wave blocks: 2 blocks/CU co-resident (3 waves/SIMD), no serialization
                  // (R4 post-mortem: 1024 -> 1 block/CU -> 2 serial rounds; 256 -> only 1.5 waves/SIMD)

__global__ __launch_bounds__(TPB) void behler_ang_kernel(
    const float* __restrict__ positions,  // (B,A,3)
    const float* __restrict__ cell,       // (B,3,3)
    const float* __restrict__ offsets,    // (B,A,N,3)
    const float* __restrict__ etas,       // (E,)
    const int*  __restrict__ zetas,       // (Z,)
    const int*  __restrict__ nbr_j,       // (B,A,T)
    const int*  __restrict__ nbr_k,       // (B,A,T)
    const int*  __restrict__ off_j,       // (B,A,T)
    const int*  __restrict__ off_k,       // (B,A,T)
    const int*  __restrict__ mask,        // (B,A,T)
    float* __restrict__ out,              // (B,A,E*2Z)
    int A, int T, int N)
{
    constexpr int E = 8, Z = 4;
    constexpr int NWAVE = TPB / 64;
    const int ba  = blockIdx.x;
    const int b   = ba / A;
    const int a   = ba - b * A;
    const int tid = threadIdx.x;

    __shared__ float sPosX[256], sPosY[256], sPosZ[256];   // A <= 256
    __shared__ float sCartX[64], sCartY[64], sCartZ[64];   // N <= 64
    __shared__ float sEta[E];
    __shared__ float sRed[NWAVE][E * Z];

    for (int i = tid; i < A; i += TPB) {
        const float* p = positions + ((size_t)b * A + i) * 3;
        sPosX[i] = p[0]; sPosY[i] = p[1]; sPosZ[i] = p[2];
    }
    const float* cb = cell + (size_t)b * 9;
    for (int n = tid; n < N; n += TPB) {
        const float* o = offsets + (((size_t)ba) * N + n) * 3;
        float ox = o[0], oy = o[1], oz = o[2];
        sCartX[n] = ox * cb[0] + oy * cb[3] + oz * cb[6];
        sCartY[n] = ox * cb[1] + oy * cb[4] + oz * cb[7];
        sCartZ[n] = ox * cb[2] + oy * cb[5] + oz * cb[8];
    }
    if (tid < E) sEta[tid] = etas[tid];
    __syncthreads();

    const float rix = sPosX[a], riy = sPosY[a], riz = sPosZ[a];

    float acc[E][Z];
    #pragma unroll
    for (int e = 0; e < E; ++e)
        #pragma unroll
        for (int z = 0; z < Z; ++z) acc[e][z] = 0.0f;

    const size_t tb = (size_t)ba * T;
    const int*  pM = mask  + tb;
    const int*  pJ = nbr_j + tb;
    const int*  pK = nbr_k + tb;
    const int*  pFJ = off_j + tb;
    const int*  pFK = off_k + tb;
    const float PI_OVER_RC = 0.6283185307179586f;  // pi / 5.0

    // ---- software-pipelined triple loop: prefetch t+TPB while computing t
    int t = tid;
    int m = 0, j = 0, k = 0, fj = 0, fk = 0;
    if (t < T) {
        m = pM[t]; j = pJ[t]; k = pK[t]; fj = pFJ[t]; fk = pFK[t];
    }
    while (t < T) {
        const int tn = t + TPB;
        int nm = 0, njx = 0, nkx = 0, nfj = 0, nfk = 0;
        if (tn < T) {   // issue next iteration's loads before current compute
            nm = pM[tn]; njx = pJ[tn]; nkx = pK[tn]; nfj = pFJ[tn]; nfk = pFK[tn];
        }

        if (m != 0) {
            float pjx = sPosX[j] + sCartX[fj];
            float pjy = sPosY[j] + sCartY[fj];
            float pjz = sPosZ[j] + sCartZ[fj];
            float pkx = sPosX[k] + sCartX[fk];
            float pky = sPosY[k] + sCartY[fk];
            float pkz = sPosZ[k] + sCartZ[fk];

            float djx = pjx - rix, djy = pjy - riy, djz = pjz - riz;
            float dkx = pkx - rix, dky = pky - riy, dkz = pkz - riz;
            float dex = pkx - pjx, dey = pky - pjy, dez = pkz - pjz;

            float d2ij = fmaxf(djx * djx + djy * djy + djz * djz, 1e-12f);
            float d2ik = fmaxf(dkx * dkx + dky * dky + dkz * dkz, 1e-12f);
            float d2jk = fmaxf(dex * dex + dey * dey + dez * dez, 1e-12f);

            // any r >= RC => cutoff = 0 => zero contribution
            if (d2ij < 25.0f && d2ik < 25.0f && d2jk < 25.0f) {
                float rij = sqrtf(d2ij), rik = sqrtf(d2ik), rjk = sqrtf(d2jk);
                float r2 = d2ij + d2ik + d2jk;

                float cut = 0.125f * (__cosf(rij * PI_OVER_RC) + 1.0f)
                                   * (__cosf(rik * PI_OVER_RC) + 1.0f)
                                   * (__cosf(rjk * PI_OVER_RC) + 1.0f);

                float cost = r2 / (2.0f * rij * rik);
                float x = 1.0f - cost;

                // zetas = {1,2,4,8}: powers by repeated squaring
                float x1 = x;
                float x2 = x1 * x1;
                float x4 = x2 * x2;
                float x8 = x4 * x4;
                float bz[Z] = { x1, x2, x4, x8 };

                #pragma unroll
                for (int e = 0; e < E; ++e) {
                    float rad = __expf(-sEta[e] * r2) * cut;
                    #pragma unroll
                    for (int z = 0; z < Z; ++z)
                        acc[e][z] = fmaf(rad, bz[z], acc[e][z]);
                }
            }
        }

        m = nm; j = njx; k = nkx; fj = nfj; fk = nfk;
        t = tn;
    }

    // ---- reduction: wave butterfly, then cross-wave via LDS ----
    const int lane = tid & 63, wave = tid >> 6;
    #pragma unroll
    for (int e = 0; e < E; ++e) {
        #pragma unroll
        for (int z = 0; z < Z; ++z) {
            float v = acc[e][z];
            v += __shfl_down(v, 32);
            v += __shfl_down(v, 16);
            v += __shfl_down(v, 8);
            v += __shfl_down(v, 4);
            v += __shfl_down(v, 2);
            v += __shfl_down(v, 1);
            if (lane == 0) sRed[wave][e * Z + z] = v;
        }
    }
    __syncthreads();

    if (tid < E * Z) {
        float v = 0.0f;
        #pragma unroll
        for (int w = 0; w < NWAVE; ++w) v += sRed[w][tid];
        int e = tid >> 2;        // Z == 4
        int z = tid & 3;
        int zt = zetas[z];
        size_t ob = (size_t)ba * (E * 2 * Z) + (size_t)e * (2 * Z);
        out[ob + z]     = ldexpf(v, 1 - zt);   // 2^(1-zeta) * v
        out[ob + Z + z] = ldexpf(v, 1 + zt);   // 2^(1+zeta) * v
    }
}

extern "C" void kernel_launch(void* const* d_in, const int* in_sizes, int n_in,
                              void* d_out, int out_size, void* d_ws, size_t ws_size,
                              hipStream_t stream) {
    const float* positions = (const float*)d_in[0];
    const float* cell      = (const float*)d_in[1];
    const float* offsets   = (const float*)d_in[2];
    const float* etas      = (const float*)d_in[3];
    const int*   zetas     = (const int*)d_in[4];
    const int*   nj        = (const int*)d_in[5];
    const int*   nk        = (const int*)d_in[6];
    const int*   oj        = (const int*)d_in[7];
    const int*   ok        = (const int*)d_in[8];
    const int*   msk       = (const int*)d_in[9];
    float* out = (float*)d_out;

    int B = in_sizes[1] / 9;
    int A = in_sizes[0] / (3 * B);
    int N = in_sizes[2] / (B * A * 3);
    int T = in_sizes[5] / (B * A);

    behler_ang_kernel<<<B * A, TPB, 0, stream>>>(
        positions, cell, offsets, etas, zetas, nj, nk, oj, ok, msk, out, A, T, N);
}

// Round 7
// 91.442 us; speedup vs baseline: 1.0182x; 1.0182x over previous
//
#include <hip/hip_runtime.h>
#include <math.h>

#define TPB 256   // best of {256, 512, 1024} sweep (R2/R5=92.0, R6=93.1, R4=103.0)

__device__ __forceinline__ void triple_accum(
    int j, int k, int fj, int fk,
    const float* __restrict__ sPosX, const float* __restrict__ sPosY,
    const float* __restrict__ sPosZ,
    const float* __restrict__ sCartX, const float* __restrict__ sCartY,
    const float* __restrict__ sCartZ,
    const float* __restrict__ sEta,
    float rix, float riy, float riz,
    float acc[8][4])
{
    const float PI_OVER_RC = 0.6283185307179586f;  // pi / 5.0
    float pjx = sPosX[j] + sCartX[fj];
    float pjy = sPosY[j] + sCartY[fj];
    float pjz = sPosZ[j] + sCartZ[fj];
    float pkx = sPosX[k] + sCartX[fk];
    float pky = sPosY[k] + sCartY[fk];
    float pkz = sPosZ[k] + sCartZ[fk];

    float djx = pjx - rix, djy = pjy - riy, djz = pjz - riz;
    float dkx = pkx - rix, dky = pky - riy, dkz = pkz - riz;
    float dex = pkx - pjx, dey = pky - pjy, dez = pkz - pjz;

    float d2ij = fmaxf(djx * djx + djy * djy + djz * djz, 1e-12f);
    float d2ik = fmaxf(dkx * dkx + dky * dky + dkz * dkz, 1e-12f);
    float d2jk = fmaxf(dex * dex + dey * dey + dez * dez, 1e-12f);

    // any r >= RC => cutoff = 0 => zero contribution
    if (d2ij >= 25.0f || d2ik >= 25.0f || d2jk >= 25.0f) return;

    float rij = sqrtf(d2ij), rik = sqrtf(d2ik), rjk = sqrtf(d2jk);
    float r2 = d2ij + d2ik + d2jk;

    float cut = 0.125f * (__cosf(rij * PI_OVER_RC) + 1.0f)
                       * (__cosf(rik * PI_OVER_RC) + 1.0f)
                       * (__cosf(rjk * PI_OVER_RC) + 1.0f);

    float cost = r2 / (2.0f * rij * rik);
    float x = 1.0f - cost;

    // zetas = {1,2,4,8}: powers by repeated squaring
    float x1 = x;
    float x2 = x1 * x1;
    float x4 = x2 * x2;
    float x8 = x4 * x4;
    float bz[4] = { x1, x2, x4, x8 };

    #pragma unroll
    for (int e = 0; e < 8; ++e) {
        float rad = __expf(-sEta[e] * r2) * cut;
        #pragma unroll
        for (int z = 0; z < 4; ++z)
            acc[e][z] = fmaf(rad, bz[z], acc[e][z]);
    }
}

__global__ __launch_bounds__(TPB) void behler_ang_kernel(
    const float* __restrict__ positions,  // (B,A,3)
    const float* __restrict__ cell,       // (B,3,3)
    const float* __restrict__ offsets,    // (B,A,N,3)
    const float* __restrict__ etas,       // (E,)
    const int*  __restrict__ zetas,       // (Z,)
    const int*  __restrict__ nbr_j,       // (B,A,T)
    const int*  __restrict__ nbr_k,       // (B,A,T)
    const int*  __restrict__ off_j,       // (B,A,T)
    const int*  __restrict__ off_k,       // (B,A,T)
    const int*  __restrict__ mask,        // (B,A,T)
    float* __restrict__ out,              // (B,A,E*2Z)
    int A, int T, int N)
{
    constexpr int E = 8, Z = 4;
    constexpr int NWAVE = TPB / 64;
    const int ba  = blockIdx.x;
    const int b   = ba / A;
    const int a   = ba - b * A;
    const int tid = threadIdx.x;

    __shared__ float sPosX[256], sPosY[256], sPosZ[256];   // A <= 256
    __shared__ float sCartX[64], sCartY[64], sCartZ[64];   // N <= 64
    __shared__ float sEta[E];
    __shared__ float sRed[NWAVE][E * Z];

    for (int i = tid; i < A; i += TPB) {
        const float* p = positions + ((size_t)b * A + i) * 3;
        sPosX[i] = p[0]; sPosY[i] = p[1]; sPosZ[i] = p[2];
    }
    const float* cb = cell + (size_t)b * 9;
    for (int n = tid; n < N; n += TPB) {
        const float* o = offsets + (((size_t)ba) * N + n) * 3;
        float ox = o[0], oy = o[1], oz = o[2];
        sCartX[n] = ox * cb[0] + oy * cb[3] + oz * cb[6];
        sCartY[n] = ox * cb[1] + oy * cb[4] + oz * cb[7];
        sCartZ[n] = ox * cb[2] + oy * cb[5] + oz * cb[8];
    }
    if (tid < E) sEta[tid] = etas[tid];
    __syncthreads();

    const float rix = sPosX[a], riy = sPosY[a], riz = sPosZ[a];

    float acc[E][Z];
    #pragma unroll
    for (int e = 0; e < E; ++e)
        #pragma unroll
        for (int z = 0; z < Z; ++z) acc[e][z] = 0.0f;

    // ---- paired-triple loop: int2 loads (5x dwordx2 instead of 10x dword),
    //      3 iterations, 2 independent compute chains per iteration, 1-deep prefetch
    const size_t tb = (size_t)ba * T;       // T even, row 8B-aligned
    const int2* pM2  = (const int2*)(mask  + tb);
    const int2* pJ2  = (const int2*)(nbr_j + tb);
    const int2* pK2  = (const int2*)(nbr_k + tb);
    const int2* pFJ2 = (const int2*)(off_j + tb);
    const int2* pFK2 = (const int2*)(off_k + tb);
    const int NP = T >> 1;                  // pairs per (b,a)

    int p = tid;
    int2 m2 = {0, 0}, j2 = {0, 0}, k2 = {0, 0}, fj2 = {0, 0}, fk2 = {0, 0};
    if (p < NP) {
        m2 = pM2[p]; j2 = pJ2[p]; k2 = pK2[p]; fj2 = pFJ2[p]; fk2 = pFK2[p];
    }
    while (p < NP) {
        const int pn = p + TPB;
        int2 nm2 = {0, 0}, nj2 = {0, 0}, nk2 = {0, 0}, nfj2 = {0, 0}, nfk2 = {0, 0};
        if (pn < NP) {   // prefetch next iteration before current compute
            nm2 = pM2[pn]; nj2 = pJ2[pn]; nk2 = pK2[pn]; nfj2 = pFJ2[pn]; nfk2 = pFK2[pn];
        }

        if (m2.x != 0)
            triple_accum(j2.x, k2.x, fj2.x, fk2.x,
                         sPosX, sPosY, sPosZ, sCartX, sCartY, sCartZ, sEta,
                         rix, riy, riz, acc);
        if (m2.y != 0)
            triple_accum(j2.y, k2.y, fj2.y, fk2.y,
                         sPosX, sPosY, sPosZ, sCartX, sCartY, sCartZ, sEta,
                         rix, riy, riz, acc);

        m2 = nm2; j2 = nj2; k2 = nk2; fj2 = nfj2; fk2 = nfk2;
        p = pn;
    }

    // ---- reduction: wave butterfly, then cross-wave via LDS ----
    const int lane = tid & 63, wave = tid >> 6;
    #pragma unroll
    for (int e = 0; e < E; ++e) {
        #pragma unroll
        for (int z = 0; z < Z; ++z) {
            float v = acc[e][z];
            v += __shfl_down(v, 32);
            v += __shfl_down(v, 16);
            v += __shfl_down(v, 8);
            v += __shfl_down(v, 4);
            v += __shfl_down(v, 2);
            v += __shfl_down(v, 1);
            if (lane == 0) sRed[wave][e * Z + z] = v;
        }
    }
    __syncthreads();

    if (tid < E * Z) {
        float v = 0.0f;
        #pragma unroll
        for (int w = 0; w < NWAVE; ++w) v += sRed[w][tid];
        int e = tid >> 2;        // Z == 4
        int z = tid & 3;
        int zt = zetas[z];
        size_t ob = (size_t)ba * (E * 2 * Z) + (size_t)e * (2 * Z);
        out[ob + z]     = ldexpf(v, 1 - zt);   // 2^(1-zeta) * v
        out[ob + Z + z] = ldexpf(v, 1 + zt);   // 2^(1+zeta) * v
    }
}

extern "C" void kernel_launch(void* const* d_in, const int* in_sizes, int n_in,
                              void* d_out, int out_size, void* d_ws, size_t ws_size,
                              hipStream_t stream) {
    const float* positions = (const float*)d_in[0];
    const float* cell      = (const float*)d_in[1];
    const float* offsets   = (const float*)d_in[2];
    const float* etas      = (const float*)d_in[3];
    const int*   zetas     = (const int*)d_in[4];
    const int*   nj        = (const int*)d_in[5];
    const int*   nk        = (const int*)d_in[6];
    const int*   oj        = (const int*)d_in[7];
    const int*   ok        = (const int*)d_in[8];
    const int*   msk       = (const int*)d_in[9];
    float* out = (float*)d_out;

    int B = in_sizes[1] / 9;
    int A = in_sizes[0] / (3 * B);
    int N = in_sizes[2] / (B * A * 3);
    int T = in_sizes[5] / (B * A);

    behler_ang_kernel<<<B * A, TPB, 0, stream>>>(
        positions, cell, offsets, etas, zetas, nj, nk, oj, ok, msk, out, A, T, N);
}

// Round 8
// 90.936 us; speedup vs baseline: 1.0238x; 1.0056x over previous
//
#include <hip/hip_runtime.h>
#include <math.h>

#define TPB 256   // best of {256,512,1024} sweep (92.0 / 93.1 / 103.0)

__device__ __forceinline__ void triple_accum(
    int j, int k, int fj, int fk,
    const float* __restrict__ sPosX, const float* __restrict__ sPosY,
    const float* __restrict__ sPosZ,
    const float* __restrict__ sCartX, const float* __restrict__ sCartY,
    const float* __restrict__ sCartZ,
    const float* __restrict__ sEta,
    float rix, float riy, float riz,
    float acc[8][4])
{
    const float PI_OVER_RC = 0.6283185307179586f;  // pi / 5.0
    float pjx = sPosX[j] + sCartX[fj];
    float pjy = sPosY[j] + sCartY[fj];
    float pjz = sPosZ[j] + sCartZ[fj];
    float pkx = sPosX[k] + sCartX[fk];
    float pky = sPosY[k] + sCartY[fk];
    float pkz = sPosZ[k] + sCartZ[fk];

    float djx = pjx - rix, djy = pjy - riy, djz = pjz - riz;
    float dkx = pkx - rix, dky = pky - riy, dkz = pkz - riz;
    float dex = pkx - pjx, dey = pky - pjy, dez = pkz - pjz;

    float d2ij = fmaxf(djx * djx + djy * djy + djz * djz, 1e-12f);
    float d2ik = fmaxf(dkx * dkx + dky * dky + dkz * dkz, 1e-12f);
    float d2jk = fmaxf(dex * dex + dey * dey + dez * dez, 1e-12f);

    // any r >= RC => cutoff = 0 => zero contribution
    if (d2ij >= 25.0f || d2ik >= 25.0f || d2jk >= 25.0f) return;

    float rij = sqrtf(d2ij), rik = sqrtf(d2ik), rjk = sqrtf(d2jk);
    float r2 = d2ij + d2ik + d2jk;

    float cut = 0.125f * (__cosf(rij * PI_OVER_RC) + 1.0f)
                       * (__cosf(rik * PI_OVER_RC) + 1.0f)
                       * (__cosf(rjk * PI_OVER_RC) + 1.0f);

    float cost = r2 / (2.0f * rij * rik);
    float x = 1.0f - cost;

    // zetas = {1,2,4,8}: powers by repeated squaring
    float x1 = x;
    float x2 = x1 * x1;
    float x4 = x2 * x2;
    float x8 = x4 * x4;
    float bz[4] = { x1, x2, x4, x8 };

    #pragma unroll
    for (int e = 0; e < 8; ++e) {
        float rad = __expf(-sEta[e] * r2) * cut;
        #pragma unroll
        for (int z = 0; z < 4; ++z)
            acc[e][z] = fmaf(rad, bz[z], acc[e][z]);
    }
}

__global__ __launch_bounds__(TPB) void behler_ang_kernel(
    const float* __restrict__ positions,  // (B,A,3)
    const float* __restrict__ cell,       // (B,3,3)
    const float* __restrict__ offsets,    // (B,A,N,3)
    const float* __restrict__ etas,       // (E,)
    const int*  __restrict__ zetas,       // (Z,)
    const int*  __restrict__ nbr_j,       // (B,A,T)
    const int*  __restrict__ nbr_k,       // (B,A,T)
    const int*  __restrict__ off_j,       // (B,A,T)
    const int*  __restrict__ off_k,       // (B,A,T)
    const int*  __restrict__ mask,        // (B,A,T)
    float* __restrict__ out,              // (B,A,E*2Z)
    int A, int T, int N)
{
    constexpr int E = 8, Z = 4;
    constexpr int NWAVE = TPB / 64;
    const int ba  = blockIdx.x;
    const int b   = ba / A;
    const int a   = ba - b * A;
    const int tid = threadIdx.x;

    __shared__ float sPosX[256], sPosY[256], sPosZ[256];   // A <= 256
    __shared__ float sCartX[64], sCartY[64], sCartZ[64];   // N <= 64
    __shared__ float sEta[E];
    __shared__ float sRed[NWAVE][E * Z];

    for (int i = tid; i < A; i += TPB) {
        const float* p = positions + ((size_t)b * A + i) * 3;
        sPosX[i] = p[0]; sPosY[i] = p[1]; sPosZ[i] = p[2];
    }
    const float* cb = cell + (size_t)b * 9;
    for (int n = tid; n < N; n += TPB) {
        const float* o = offsets + (((size_t)ba) * N + n) * 3;
        float ox = o[0], oy = o[1], oz = o[2];
        sCartX[n] = ox * cb[0] + oy * cb[3] + oz * cb[6];
        sCartY[n] = ox * cb[1] + oy * cb[4] + oz * cb[7];
        sCartZ[n] = ox * cb[2] + oy * cb[5] + oz * cb[8];
    }
    if (tid < E) sEta[tid] = etas[tid];
    __syncthreads();

    const float rix = sPosX[a], riy = sPosY[a], riz = sPosZ[a];

    float acc[E][Z];
    #pragma unroll
    for (int e = 0; e < E; ++e)
        #pragma unroll
        for (int z = 0; z < Z; ++z) acc[e][z] = 0.0f;

    const size_t tb = (size_t)ba * T;       // T even, row 8B-aligned
    const int2* pM2  = (const int2*)(mask  + tb);
    const int2* pJ2  = (const int2*)(nbr_j + tb);
    const int2* pK2  = (const int2*)(nbr_k + tb);
    const int2* pFJ2 = (const int2*)(off_j + tb);
    const int2* pFK2 = (const int2*)(off_k + tb);
    const int NP = T >> 1;                  // pairs per (b,a)

    if (NP == 3 * TPB) {
        // ---- fully-unrolled path: issue ALL 15 dwordx2 loads up front (one
        // latency window for the thread's entire 120 B working set), then
        // compute the 6 triples with no remaining memory dependencies.
        int2 m2[3], j2[3], k2[3], fj2[3], fk2[3];
        #pragma unroll
        for (int i = 0; i < 3; ++i) {
            const int p = tid + i * TPB;
            m2[i]  = pM2[p];
            j2[i]  = pJ2[p];
            k2[i]  = pK2[p];
            fj2[i] = pFJ2[p];
            fk2[i] = pFK2[p];
        }
        #pragma unroll
        for (int i = 0; i < 3; ++i) {
            if (m2[i].x != 0)
                triple_accum(j2[i].x, k2[i].x, fj2[i].x, fk2[i].x,
                             sPosX, sPosY, sPosZ, sCartX, sCartY, sCartZ, sEta,
                             rix, riy, riz, acc);
            if (m2[i].y != 0)
                triple_accum(j2[i].y, k2[i].y, fj2[i].y, fk2[i].y,
                             sPosX, sPosY, sPosZ, sCartX, sCartY, sCartZ, sEta,
                             rix, riy, riz, acc);
        }
    } else {
        // ---- generic fallback: 1-deep pipelined paired loop
        int p = tid;
        int2 m2 = {0,0}, j2 = {0,0}, k2 = {0,0}, fj2 = {0,0}, fk2 = {0,0};
        if (p < NP) {
            m2 = pM2[p]; j2 = pJ2[p]; k2 = pK2[p]; fj2 = pFJ2[p]; fk2 = pFK2[p];
        }
        while (p < NP) {
            const int pn = p + TPB;
            int2 nm2 = {0,0}, nj2 = {0,0}, nk2 = {0,0}, nfj2 = {0,0}, nfk2 = {0,0};
            if (pn < NP) {
                nm2 = pM2[pn]; nj2 = pJ2[pn]; nk2 = pK2[pn]; nfj2 = pFJ2[pn]; nfk2 = pFK2[pn];
            }
            if (m2.x != 0)
                triple_accum(j2.x, k2.x, fj2.x, fk2.x,
                             sPosX, sPosY, sPosZ, sCartX, sCartY, sCartZ, sEta,
                             rix, riy, riz, acc);
            if (m2.y != 0)
                triple_accum(j2.y, k2.y, fj2.y, fk2.y,
                             sPosX, sPosY, sPosZ, sCartX, sCartY, sCartZ, sEta,
                             rix, riy, riz, acc);
            m2 = nm2; j2 = nj2; k2 = nk2; fj2 = nfj2; fk2 = nfk2;
            p = pn;
        }
    }

    // ---- reduction: wave butterfly, then cross-wave via LDS ----
    const int lane = tid & 63, wave = tid >> 6;
    #pragma unroll
    for (int e = 0; e < E; ++e) {
        #pragma unroll
        for (int z = 0; z < Z; ++z) {
            float v = acc[e][z];
            v += __shfl_down(v, 32);
            v += __shfl_down(v, 16);
            v += __shfl_down(v, 8);
            v += __shfl_down(v, 4);
            v += __shfl_down(v, 2);
            v += __shfl_down(v, 1);
            if (lane == 0) sRed[wave][e * Z + z] = v;
        }
    }
    __syncthreads();

    if (tid < E * Z) {
        float v = 0.0f;
        #pragma unroll
        for (int w = 0; w < NWAVE; ++w) v += sRed[w][tid];
        int e = tid >> 2;        // Z == 4
        int z = tid & 3;
        int zt = zetas[z];
        size_t ob = (size_t)ba * (E * 2 * Z) + (size_t)e * (2 * Z);
        out[ob + z]     = ldexpf(v, 1 - zt);   // 2^(1-zeta) * v
        out[ob + Z + z] = ldexpf(v, 1 + zt);   // 2^(1+zeta) * v
    }
}

extern "C" void kernel_launch(void* const* d_in, const int* in_sizes, int n_in,
                              void* d_out, int out_size, void* d_ws, size_t ws_size,
                              hipStream_t stream) {
    const float* positions = (const float*)d_in[0];
    const float* cell      = (const float*)d_in[1];
    const float* offsets   = (const float*)d_in[2];
    const float* etas      = (const float*)d_in[3];
    const int*   zetas     = (const int*)d_in[4];
    const int*   nj        = (const int*)d_in[5];
    const int*   nk        = (const int*)d_in[6];
    const int*   oj        = (const int*)d_in[7];
    const int*   ok        = (const int*)d_in[8];
    const int*   msk       = (const int*)d_in[9];
    float* out = (float*)d_out;

    int B = in_sizes[1] / 9;
    int A = in_sizes[0] / (3 * B);
    int N = in_sizes[2] / (B * A * 3);
    int T = in_sizes[5] / (B * A);

    behler_ang_kernel<<<B * A, TPB, 0, stream>>>(
        positions, cell, offsets, etas, zetas, nj, nk, oj, ok, msk, out, A, T, N);
}